// Round 13
// baseline (514.578 us; speedup 1.0000x reference)
//
#include <hip/hip_runtime.h>

#define N_NODES 50000
#define N_EDGES 800000
// dims: IN=HID=256, OUT=2

static inline int cdiv(int a, int b) { return (a + b - 1) / b; }

typedef __attribute__((ext_vector_type(8))) short bf16x8;
typedef __attribute__((ext_vector_type(4))) float f32x4;

static __device__ __forceinline__ unsigned short f2bf(float f) {
    unsigned int u = __float_as_uint(f);
    unsigned int r = (u + 0x7FFF + ((u >> 16) & 1)) >> 16;  // RNE
    return (unsigned short)r;
}
static __device__ __forceinline__ float bf2f(unsigned short h) {
    return __uint_as_float((unsigned int)h << 16);
}
static __device__ __forceinline__ float bf_lo(unsigned int u) { return __uint_as_float(u << 16); }
static __device__ __forceinline__ float bf_hi(unsigned int u) { return __uint_as_float(u & 0xFFFF0000u); }

// Column permutation (per 64-col block): phys p -> logical c
static __device__ __forceinline__ int logc(int p) {
    int pl = p & 63;
    return (p & ~63) + (pl & 3) * 16 + (pl >> 2);
}

// accumulate 8 bf16 lanes of v (uint4) scaled by wgt into acc[0..7]
static __device__ __forceinline__ void acc8(float* acc, uint4 v, float wgt) {
    acc[0] += wgt * bf_lo(v.x);
    acc[1] += wgt * bf_hi(v.x);
    acc[2] += wgt * bf_lo(v.y);
    acc[3] += wgt * bf_hi(v.y);
    acc[4] += wgt * bf_lo(v.z);
    acc[5] += wgt * bf_hi(v.z);
    acc[6] += wgt * bf_lo(v.w);
    acc[7] += wgt * bf_hi(v.w);
}

// ---------------- CSR build ----------------
// cnt starts memset to 0; holds edge-indegree only (self-loop folded into scan1).

__global__ void k_count(const int* __restrict__ edst, int* cnt, int e) {
    int i = blockIdx.x * 256 + threadIdx.x;
    if (i < e) atomicAdd(&cnt[edst[i]], 1);
}

__global__ __launch_bounds__(256) void k_scan1(const int* __restrict__ cnt,
                                               int* __restrict__ row_ptr,
                                               float* __restrict__ dis,
                                               int* __restrict__ blk, int n) {
    __shared__ int sums[256];
    int t = threadIdx.x;
    int base = blockIdx.x * 1024 + t * 4;
    int c0 = 0, c1 = 0, c2 = 0, c3 = 0;
    if (base + 3 < n) {
        int4 v = *(const int4*)(cnt + base);
        c0 = v.x + 1; c1 = v.y + 1; c2 = v.z + 1; c3 = v.w + 1;  // +1 self-loop
    } else {
        if (base + 0 < n) c0 = cnt[base + 0] + 1;
        if (base + 1 < n) c1 = cnt[base + 1] + 1;
        if (base + 2 < n) c2 = cnt[base + 2] + 1;
        if (base + 3 < n) c3 = cnt[base + 3] + 1;
    }
    int s = c0 + c1 + c2 + c3;
    sums[t] = s;
    __syncthreads();
    int x = s;
    for (int off = 1; off < 256; off <<= 1) {
        int y = (t >= off) ? sums[t - off] : 0;
        __syncthreads();
        x += y;
        sums[t] = x;
        __syncthreads();
    }
    int excl = x - s;
    if (base + 0 < n) { row_ptr[base + 0] = excl;                dis[base + 0] = rsqrtf((float)c0); }
    if (base + 1 < n) { row_ptr[base + 1] = excl + c0;           dis[base + 1] = rsqrtf((float)c1); }
    if (base + 2 < n) { row_ptr[base + 2] = excl + c0 + c1;      dis[base + 2] = rsqrtf((float)c2); }
    if (base + 3 < n) { row_ptr[base + 3] = excl + c0 + c1 + c2; dis[base + 3] = rsqrtf((float)c3); }
    if (t == 255) blk[blockIdx.x] = x;
}

__global__ __launch_bounds__(256) void k_scan2(int* __restrict__ blk,
                                               int* __restrict__ row_ptr_n, int nb) {
    __shared__ int sums[256];
    int t = threadIdx.x;
    int s = (t < nb) ? blk[t] : 0;
    sums[t] = s;
    __syncthreads();
    int x = s;
    for (int off = 1; off < 256; off <<= 1) {
        int y = (t >= off) ? sums[t - off] : 0;
        __syncthreads();
        x += y;
        sums[t] = x;
        __syncthreads();
    }
    if (t < nb) blk[t] = x - s;
    if (t == 255) row_ptr_n[0] = x;
}

__global__ __launch_bounds__(256) void k_scan3(int* __restrict__ row_ptr,
                                               int* __restrict__ pos,
                                               const int* __restrict__ blk, int n) {
    int base = blockIdx.x * 1024 + threadIdx.x * 4;
    int off = blk[blockIdx.x];
#pragma unroll
    for (int i = 0; i < 4; ++i) {
        int idx = base + i;
        if (idx < n) {
            int v = row_ptr[idx] + off;
            row_ptr[idx] = v;
            pos[idx] = v;
        }
    }
}

// merged: items [0,E) = edges, [E, E+N) = self-loops.
// interleaved edge record: int2{src, float_bits(norm)} -> one 8B store per edge.
__global__ void k_fill(const int* __restrict__ esrc, const int* __restrict__ edst,
                       int* pos, const float* __restrict__ dis,
                       int2* __restrict__ eg, int e, int n) {
    int i = blockIdx.x * 256 + threadIdx.x;
    if (i < e) {
        int s = esrc[i], d = edst[i];
        int p = atomicAdd(&pos[d], 1);
        eg[p] = make_int2(s, __float_as_int(dis[s] * dis[d]));
    } else if (i < e + n) {
        int v = i - e;
        int p = atomicAdd(&pos[v], 1);
        float dv = dis[v];
        eg[p] = make_int2(v, __float_as_int(dv * dv));
    }
}

// ---------------- prep: weight split (3 layers) + x cast, one launch ----------------

__global__ __launch_bounds__(256) void k_prep(const float* __restrict__ W0,
                                              const float* __restrict__ W1,
                                              const float* __restrict__ W2,
                                              unsigned short* __restrict__ Wth,
                                              unsigned short* __restrict__ Wtl,
                                              const float* __restrict__ X,
                                              unsigned short* __restrict__ Xh, long total4) {
    if (blockIdx.x < 768) {
        int layer = blockIdx.x >> 8;
        int n = blockIdx.x & 255;
        int p = threadIdx.x;
        const float* W = layer == 0 ? W0 : (layer == 1 ? W1 : W2);
        int k = (layer != 0) ? logc(p) : p;
        float v = W[(size_t)k * 256 + n];
        unsigned short h = f2bf(v);
        size_t o = (size_t)layer * 65536 + (size_t)n * 256 + p;
        Wth[o] = h;
        Wtl[o] = f2bf(v - bf2f(h));
    } else {
        long i = (long)(blockIdx.x - 768) * 256 + threadIdx.x;
        if (i >= total4) return;
        float4 v = *(const float4*)(X + i * 4);
        ushort4 h;
        h.x = f2bf(v.x);
        h.y = f2bf(v.y);
        h.z = f2bf(v.z);
        h.w = f2bf(v.w);
        *(ushort4*)(Xh + i * 4) = h;
    }
}

// ---------------- MFMA GEMM: Ah(bf16)[M,256] @ Wsplit -> bf16 [M,256] ----
// block: 256 rows x 64 cols (784 blocks); wave: 64 rows (4 mt) x 64 cols (4 nt).
// TWO-PASS K-loop over ONE 33.8 KB LDS buffer (hi then lo) -> 4 blocks/CU.
// C = sum(ah*bh) + sum(ah*bl).  Output cols in MFMA-native (permuted) order.

#define GEMM_RB 196  // cdiv(50000,256)

__global__ __launch_bounds__(256) void k_gemm_mfma(const unsigned short* __restrict__ Ah,
                                                   const unsigned short* __restrict__ Wth,
                                                   const unsigned short* __restrict__ Wtl,
                                                   unsigned short* __restrict__ C, int M) {
    __shared__ unsigned short Wb[64][264];
    int rowblk = blockIdx.x % GEMM_RB;
    int colblk = blockIdx.x / GEMM_RB;
    int c0 = colblk * 64;
    int m0 = rowblk * 256;
    int t = threadIdx.x;
    int sr = t >> 2;
    int sk0 = (t & 3) * 64;

    int lane = t & 63, wave = t >> 6;
    int quad = lane >> 4, l16 = lane & 15;

    const unsigned short* aph[4];
#pragma unroll
    for (int mt = 0; mt < 4; ++mt) {
        int m = m0 + wave * 64 + mt * 16 + l16;
        if (m >= M) m = M - 1;  // clamp loads; stores guarded
        aph[mt] = Ah + (size_t)m * 256 + quad * 8;
    }

    f32x4 acc[4][4];
#pragma unroll
    for (int i = 0; i < 4; ++i)
#pragma unroll
        for (int j = 0; j < 4; ++j) acc[i][j] = (f32x4){0.f, 0.f, 0.f, 0.f};

    // ---- pass 1: hi ----
    {
        const unsigned short* gh = Wth + (size_t)(c0 + sr) * 256 + sk0;
        unsigned short* lh = &Wb[sr][sk0];
#pragma unroll
        for (int i = 0; i < 8; ++i)
            *(uint4*)(lh + i * 8) = *(const uint4*)(gh + i * 8);
    }
    __syncthreads();
#pragma unroll 2
    for (int kc = 0; kc < 8; ++kc) {
        int ko = kc * 32;
        bf16x8 ahf[4];
#pragma unroll
        for (int mt = 0; mt < 4; ++mt) ahf[mt] = *(const bf16x8*)(aph[mt] + ko);
#pragma unroll
        for (int nt = 0; nt < 4; ++nt) {
            bf16x8 bh = *(const bf16x8*)&Wb[nt * 16 + l16][ko + quad * 8];
#pragma unroll
            for (int mt = 0; mt < 4; ++mt)
                acc[mt][nt] = __builtin_amdgcn_mfma_f32_16x16x32_bf16(ahf[mt], bh, acc[mt][nt], 0, 0, 0);
        }
    }
    __syncthreads();

    // ---- pass 2: lo ----
    {
        const unsigned short* gl = Wtl + (size_t)(c0 + sr) * 256 + sk0;
        unsigned short* ll = &Wb[sr][sk0];
#pragma unroll
        for (int i = 0; i < 8; ++i)
            *(uint4*)(ll + i * 8) = *(const uint4*)(gl + i * 8);
    }
    __syncthreads();
#pragma unroll 2
    for (int kc = 0; kc < 8; ++kc) {
        int ko = kc * 32;
        bf16x8 ahf[4];
#pragma unroll
        for (int mt = 0; mt < 4; ++mt) ahf[mt] = *(const bf16x8*)(aph[mt] + ko);
#pragma unroll
        for (int nt = 0; nt < 4; ++nt) {
            bf16x8 bl = *(const bf16x8*)&Wb[nt * 16 + l16][ko + quad * 8];
#pragma unroll
            for (int mt = 0; mt < 4; ++mt)
                acc[mt][nt] = __builtin_amdgcn_mfma_f32_16x16x32_bf16(ahf[mt], bl, acc[mt][nt], 0, 0, 0);
        }
    }

    // permuted store: per (mt,r) one ushort4 at phys cols c0 + l16*4 + {0..3}
#pragma unroll
    for (int mt = 0; mt < 4; ++mt) {
#pragma unroll
        for (int r = 0; r < 4; ++r) {
            int row = m0 + wave * 64 + mt * 16 + quad * 4 + r;
            if (row < M) {
                ushort4 sv;
                sv.x = f2bf(acc[mt][0][r]);
                sv.y = f2bf(acc[mt][1][r]);
                sv.z = f2bf(acc[mt][2][r]);
                sv.w = f2bf(acc[mt][3][r]);
                *(ushort4*)(C + (size_t)row * 256 + c0 + l16 * 4) = sv;
            }
        }
    }
}

// ---------------- aggregation dim=256 over (permuted) bf16 messages ----------------
// wave per node, half-wave per edge, 4 edges in flight per half-wave.

__global__ __launch_bounds__(256) void k_agg256(const unsigned short* __restrict__ t,
                                                const int* __restrict__ row_ptr,
                                                const int2* __restrict__ eg,
                                                const float* __restrict__ bias,
                                                unsigned short* __restrict__ outh, int n) {
    int lane = threadIdx.x & 63;
    int wave = threadIdx.x >> 6;
    int node = blockIdx.x * 4 + wave;
    if (node >= n) return;
    int half = lane >> 5;
    int fl = lane & 31;
    int beg = row_ptr[node], end = row_ptr[node + 1];
    float acc[8] = {};
    const unsigned short* tp = t + fl * 8;

    int e = beg + half;
    for (; e + 6 < end; e += 8) {
        int2 a = eg[e], b = eg[e + 2], c = eg[e + 4], d = eg[e + 6];
        uint4 v0 = *(const uint4*)(tp + (size_t)a.x * 256);
        uint4 v1 = *(const uint4*)(tp + (size_t)b.x * 256);
        uint4 v2 = *(const uint4*)(tp + (size_t)c.x * 256);
        uint4 v3 = *(const uint4*)(tp + (size_t)d.x * 256);
        acc8(acc, v0, __int_as_float(a.y));
        acc8(acc, v1, __int_as_float(b.y));
        acc8(acc, v2, __int_as_float(c.y));
        acc8(acc, v3, __int_as_float(d.y));
    }
    for (; e + 2 < end; e += 4) {
        int2 a = eg[e], b = eg[e + 2];
        uint4 v0 = *(const uint4*)(tp + (size_t)a.x * 256);
        uint4 v1 = *(const uint4*)(tp + (size_t)b.x * 256);
        acc8(acc, v0, __int_as_float(a.y));
        acc8(acc, v1, __int_as_float(b.y));
    }
    if (e < end) {
        int2 a = eg[e];
        uint4 v0 = *(const uint4*)(tp + (size_t)a.x * 256);
        acc8(acc, v0, __int_as_float(a.y));
    }

#pragma unroll
    for (int i = 0; i < 8; ++i) acc[i] += __shfl_xor(acc[i], 32);

    if (half == 0) {
        ushort4 h0, h1;
#pragma unroll
        for (int j = 0; j < 8; ++j) {
            int cb = logc(fl * 8 + j);
            float v = acc[j] + bias[cb];
            v = v > 0.f ? v : 0.f;
            unsigned short h = f2bf(v);
            if (j == 0) h0.x = h;
            else if (j == 1) h0.y = h;
            else if (j == 2) h0.z = h;
            else if (j == 3) h0.w = h;
            else if (j == 4) h1.x = h;
            else if (j == 5) h1.y = h;
            else if (j == 6) h1.z = h;
            else h1.w = h;
        }
        unsigned short* oh = outh + (size_t)node * 256 + fl * 8;
        *(ushort4*)(oh + 0) = h0;
        *(ushort4*)(oh + 4) = h1;
    }
}

// ---------------- final projection [N,256]@[256,2] from (permuted) bf16 h ----------------

__global__ __launch_bounds__(256) void k_gemm_out2(const unsigned short* __restrict__ Hh,
                                                   const float* __restrict__ W3,
                                                   float* __restrict__ t2, int n) {
    int lane = threadIdx.x & 63;
    int wave = threadIdx.x >> 6;
    int row = blockIdx.x * 4 + wave;
    if (row >= n) return;
    ushort4 ah = *(const ushort4*)(Hh + (size_t)row * 256 + lane * 4);
    float v[4];
    v[0] = bf2f(ah.x);
    v[1] = bf2f(ah.y);
    v[2] = bf2f(ah.z);
    v[3] = bf2f(ah.w);
    float s0 = 0.f, s1 = 0.f;
#pragma unroll
    for (int i = 0; i < 4; ++i) {
        int c = logc(lane * 4 + i);
        float2 w = *(const float2*)(W3 + (size_t)c * 2);
        s0 += v[i] * w.x;
        s1 += v[i] * w.y;
    }
#pragma unroll
    for (int off = 32; off > 0; off >>= 1) {
        s0 += __shfl_down(s0, off);
        s1 += __shfl_down(s1, off);
    }
    if (lane == 0) {
        t2[(size_t)row * 2 + 0] = s0;
        t2[(size_t)row * 2 + 1] = s1;
    }
}

__global__ void k_agg2(const float* __restrict__ t2,
                       const int* __restrict__ row_ptr,
                       const int2* __restrict__ eg,
                       const float* __restrict__ b3,
                       float* __restrict__ out, int n) {
    int node = blockIdx.x * 256 + threadIdx.x;
    if (node >= n) return;
    int beg = row_ptr[node], end = row_ptr[node + 1];
    float a0 = 0.f, a1 = 0.f;
    for (int e = beg; e < end; ++e) {
        int2 m = eg[e];
        float w = __int_as_float(m.y);
        float2 v = *(const float2*)(t2 + (size_t)m.x * 2);
        a0 += w * v.x;
        a1 += w * v.y;
    }
    out[(size_t)node * 2 + 0] = a0 + b3[0];
    out[(size_t)node * 2 + 1] = a1 + b3[1];
}

// ---------------- launch ----------------

extern "C" void kernel_launch(void* const* d_in, const int* in_sizes, int n_in,
                              void* d_out, int out_size, void* d_ws, size_t ws_size,
                              hipStream_t stream) {
    const int N = N_NODES, E = N_EDGES;
    const float* x  = (const float*)d_in[0];
    const int* ei   = (const int*)d_in[1];
    const int* esrc = ei;
    const int* edst = ei + E;
    const float* W0 = (const float*)d_in[2];
    const float* b0 = (const float*)d_in[3];
    const float* W1 = (const float*)d_in[4];
    const float* b1 = (const float*)d_in[5];
    const float* W2 = (const float*)d_in[6];
    const float* b2 = (const float*)d_in[7];
    const float* W3 = (const float*)d_in[8];
    const float* b3 = (const float*)d_in[9];
    float* out = (float*)d_out;

    // workspace carve (8B-aligned regions first)
    unsigned short* Ahh = (unsigned short*)d_ws;            // N*256 bf16 h
    unsigned short* Tb  = Ahh + (size_t)N * 256;            // N*256 bf16 messages
    unsigned short* Wth = Tb + (size_t)N * 256;             // 3 x 256*256
    unsigned short* Wtl = Wth + 3 * 65536;                  // 3 x 256*256
    int2*  eg     = (int2*)(Wtl + 3 * 65536);               // E+N interleaved edge recs
    float* t2     = (float*)(eg + (E + N));                 // N*2
    float* dis    = t2 + (size_t)N * 2;                     // N
    int*   cnt    = (int*)(dis + N);                        // N
    int*   row_ptr= cnt + N;                                // N+1
    int*   pos    = row_ptr + (N + 1);                      // N
    int*   blk    = pos + N;                                // cdiv(N,1024)

    const int NB = cdiv(N, 1024);

    // CSR build
    hipMemsetAsync(cnt, 0, (size_t)N * sizeof(int), stream);
    k_count<<<cdiv(E, 256), 256, 0, stream>>>(edst, cnt, E);
    k_scan1<<<NB, 256, 0, stream>>>(cnt, row_ptr, dis, blk, N);
    k_scan2<<<1, 256, 0, stream>>>(blk, row_ptr + N, NB);
    k_scan3<<<NB, 256, 0, stream>>>(row_ptr, pos, blk, N);
    k_fill<<<cdiv(E + N, 256), 256, 0, stream>>>(esrc, edst, pos, dis, eg, E, N);

    const int ggrid = GEMM_RB * 4;
    const int agrid = cdiv(N, 4);
    const long total4 = (long)N * 64;
    const int CA = cdiv((int)total4, 256);

    k_prep<<<768 + CA, 256, 0, stream>>>(W0, W1, W2, Wth, Wtl, x, Ahh, total4);

    // layer 0
    k_gemm_mfma<<<ggrid, 256, 0, stream>>>(Ahh, Wth, Wtl, Tb, N);
    k_agg256<<<agrid, 256, 0, stream>>>(Tb, row_ptr, eg, b0, Ahh, N);
    // layer 1
    k_gemm_mfma<<<ggrid, 256, 0, stream>>>(Ahh, Wth + 65536, Wtl + 65536, Tb, N);
    k_agg256<<<agrid, 256, 0, stream>>>(Tb, row_ptr, eg, b1, Ahh, N);
    // layer 2
    k_gemm_mfma<<<ggrid, 256, 0, stream>>>(Ahh, Wth + 2 * 65536, Wtl + 2 * 65536, Tb, N);
    k_agg256<<<agrid, 256, 0, stream>>>(Tb, row_ptr, eg, b2, Ahh, N);
    // layer 3 (no relu)
    k_gemm_out2<<<agrid, 256, 0, stream>>>(Ahh, W3, t2, N);
    k_agg2<<<cdiv(N, 256), 256, 0, stream>>>(t2, row_ptr, eg, b3, out, N);
}

// Round 14
// 475.288 us; speedup vs baseline: 1.0827x; 1.0827x over previous
//
#include <hip/hip_runtime.h>

#define N_NODES 50000
#define N_EDGES 800000
// dims: IN=HID=256, OUT=2

static inline int cdiv(int a, int b) { return (a + b - 1) / b; }

typedef __attribute__((ext_vector_type(8))) short bf16x8;
typedef __attribute__((ext_vector_type(4))) float f32x4;

static __device__ __forceinline__ unsigned short f2bf(float f) {
    unsigned int u = __float_as_uint(f);
    unsigned int r = (u + 0x7FFF + ((u >> 16) & 1)) >> 16;  // RNE
    return (unsigned short)r;
}
static __device__ __forceinline__ float bf2f(unsigned short h) {
    return __uint_as_float((unsigned int)h << 16);
}
static __device__ __forceinline__ float bf_lo(unsigned int u) { return __uint_as_float(u << 16); }
static __device__ __forceinline__ float bf_hi(unsigned int u) { return __uint_as_float(u & 0xFFFF0000u); }

// Column permutation (per 64-col block): phys p -> logical c
static __device__ __forceinline__ int logc(int p) {
    int pl = p & 63;
    return (p & ~63) + (pl & 3) * 16 + (pl >> 2);
}

// accumulate 8 bf16 lanes of v (uint4) scaled by wgt into acc[0..7]
static __device__ __forceinline__ void acc8(float* acc, uint4 v, float wgt) {
    acc[0] += wgt * bf_lo(v.x);
    acc[1] += wgt * bf_hi(v.x);
    acc[2] += wgt * bf_lo(v.y);
    acc[3] += wgt * bf_hi(v.y);
    acc[4] += wgt * bf_lo(v.z);
    acc[5] += wgt * bf_hi(v.z);
    acc[6] += wgt * bf_lo(v.w);
    acc[7] += wgt * bf_hi(v.w);
}

// ---------------- CSR build ----------------
// cnt starts memset to 0; holds edge-indegree only (self-loop folded into scan1).

__global__ void k_count(const int* __restrict__ edst, int* cnt, int e) {
    int i = blockIdx.x * 256 + threadIdx.x;
    if (i < e) atomicAdd(&cnt[edst[i]], 1);
}

__global__ __launch_bounds__(256) void k_scan1(const int* __restrict__ cnt,
                                               int* __restrict__ row_ptr,
                                               float* __restrict__ dis,
                                               int* __restrict__ blk, int n) {
    __shared__ int sums[256];
    int t = threadIdx.x;
    int base = blockIdx.x * 1024 + t * 4;
    int c0 = 0, c1 = 0, c2 = 0, c3 = 0;
    if (base + 3 < n) {
        int4 v = *(const int4*)(cnt + base);
        c0 = v.x + 1; c1 = v.y + 1; c2 = v.z + 1; c3 = v.w + 1;  // +1 self-loop
    } else {
        if (base + 0 < n) c0 = cnt[base + 0] + 1;
        if (base + 1 < n) c1 = cnt[base + 1] + 1;
        if (base + 2 < n) c2 = cnt[base + 2] + 1;
        if (base + 3 < n) c3 = cnt[base + 3] + 1;
    }
    int s = c0 + c1 + c2 + c3;
    sums[t] = s;
    __syncthreads();
    int x = s;
    for (int off = 1; off < 256; off <<= 1) {
        int y = (t >= off) ? sums[t - off] : 0;
        __syncthreads();
        x += y;
        sums[t] = x;
        __syncthreads();
    }
    int excl = x - s;
    if (base + 0 < n) { row_ptr[base + 0] = excl;                dis[base + 0] = rsqrtf((float)c0); }
    if (base + 1 < n) { row_ptr[base + 1] = excl + c0;           dis[base + 1] = rsqrtf((float)c1); }
    if (base + 2 < n) { row_ptr[base + 2] = excl + c0 + c1;      dis[base + 2] = rsqrtf((float)c2); }
    if (base + 3 < n) { row_ptr[base + 3] = excl + c0 + c1 + c2; dis[base + 3] = rsqrtf((float)c3); }
    if (t == 255) blk[blockIdx.x] = x;
}

__global__ __launch_bounds__(256) void k_scan2(int* __restrict__ blk,
                                               int* __restrict__ row_ptr_n, int nb) {
    __shared__ int sums[256];
    int t = threadIdx.x;
    int s = (t < nb) ? blk[t] : 0;
    sums[t] = s;
    __syncthreads();
    int x = s;
    for (int off = 1; off < 256; off <<= 1) {
        int y = (t >= off) ? sums[t - off] : 0;
        __syncthreads();
        x += y;
        sums[t] = x;
        __syncthreads();
    }
    if (t < nb) blk[t] = x - s;
    if (t == 255) row_ptr_n[0] = x;
}

__global__ __launch_bounds__(256) void k_scan3(int* __restrict__ row_ptr,
                                               int* __restrict__ pos,
                                               const int* __restrict__ blk, int n) {
    int base = blockIdx.x * 1024 + threadIdx.x * 4;
    int off = blk[blockIdx.x];
#pragma unroll
    for (int i = 0; i < 4; ++i) {
        int idx = base + i;
        if (idx < n) {
            int v = row_ptr[idx] + off;
            row_ptr[idx] = v;
            pos[idx] = v;
        }
    }
}

// merged: items [0,E) = edges, [E, E+N) = self-loops.
// interleaved edge record: int2{src, float_bits(norm)} -> one 8B store per edge.
__global__ void k_fill(const int* __restrict__ esrc, const int* __restrict__ edst,
                       int* pos, const float* __restrict__ dis,
                       int2* __restrict__ eg, int e, int n) {
    int i = blockIdx.x * 256 + threadIdx.x;
    if (i < e) {
        int s = esrc[i], d = edst[i];
        int p = atomicAdd(&pos[d], 1);
        eg[p] = make_int2(s, __float_as_int(dis[s] * dis[d]));
    } else if (i < e + n) {
        int v = i - e;
        int p = atomicAdd(&pos[v], 1);
        float dv = dis[v];
        eg[p] = make_int2(v, __float_as_int(dv * dv));
    }
}

// ---------------- prep: weight split (3 layers) + x cast, one launch ----------------

__global__ __launch_bounds__(256) void k_prep(const float* __restrict__ W0,
                                              const float* __restrict__ W1,
                                              const float* __restrict__ W2,
                                              unsigned short* __restrict__ Wth,
                                              unsigned short* __restrict__ Wtl,
                                              const float* __restrict__ X,
                                              unsigned short* __restrict__ Xh, long total4) {
    if (blockIdx.x < 768) {
        int layer = blockIdx.x >> 8;
        int n = blockIdx.x & 255;
        int p = threadIdx.x;
        const float* W = layer == 0 ? W0 : (layer == 1 ? W1 : W2);
        int k = (layer != 0) ? logc(p) : p;
        float v = W[(size_t)k * 256 + n];
        unsigned short h = f2bf(v);
        size_t o = (size_t)layer * 65536 + (size_t)n * 256 + p;
        Wth[o] = h;
        Wtl[o] = f2bf(v - bf2f(h));
    } else {
        long i = (long)(blockIdx.x - 768) * 256 + threadIdx.x;
        if (i >= total4) return;
        float4 v = *(const float4*)(X + i * 4);
        ushort4 h;
        h.x = f2bf(v.x);
        h.y = f2bf(v.y);
        h.z = f2bf(v.z);
        h.w = f2bf(v.w);
        *(ushort4*)(Xh + i * 4) = h;
    }
}

// ---------------- MFMA GEMM: Ah(bf16)[M,256] @ Wsplit -> bf16 [M,256] ----
// block: 256 rows x 64 cols (784 blocks); wave: 64 rows (4 mt) x 64 cols (4 nt).
// C = ah*bh + ah*bl, BOTH products inside each kc (32 MFMAs/interval).
// LDS: Wh full-K (33.8 KB) + Wl half-K (17.4 KB) restaged once mid-kernel
// -> 51.2 KB -> 3 blocks/CU (vs 2 at 67.6 KB).

#define GEMM_RB 196  // cdiv(50000,256)

__global__ __launch_bounds__(256) void k_gemm_mfma(const unsigned short* __restrict__ Ah,
                                                   const unsigned short* __restrict__ Wth,
                                                   const unsigned short* __restrict__ Wtl,
                                                   unsigned short* __restrict__ C, int M) {
    __shared__ unsigned short Wh[64][264];  // full K, pad 8 -> 2-way (free)
    __shared__ unsigned short Wl[64][136];  // half K, pad 8
    int rowblk = blockIdx.x % GEMM_RB;
    int colblk = blockIdx.x / GEMM_RB;
    int c0 = colblk * 64;
    int m0 = rowblk * 256;
    int t = threadIdx.x;
    int sr = t >> 2;

    {   // stage Wh (full 256 k) + Wl first half (k 0..127)
        int hk0 = (t & 3) * 64;
        const unsigned short* gh = Wth + (size_t)(c0 + sr) * 256 + hk0;
        unsigned short* lh = &Wh[sr][hk0];
#pragma unroll
        for (int i = 0; i < 8; ++i)
            *(uint4*)(lh + i * 8) = *(const uint4*)(gh + i * 8);
        int lk0 = (t & 3) * 32;
        const unsigned short* gl = Wtl + (size_t)(c0 + sr) * 256 + lk0;
        unsigned short* ll = &Wl[sr][lk0];
#pragma unroll
        for (int i = 0; i < 4; ++i)
            *(uint4*)(ll + i * 8) = *(const uint4*)(gl + i * 8);
    }
    __syncthreads();

    int lane = t & 63, wave = t >> 6;
    int quad = lane >> 4, l16 = lane & 15;

    const unsigned short* aph[4];
#pragma unroll
    for (int mt = 0; mt < 4; ++mt) {
        int m = m0 + wave * 64 + mt * 16 + l16;
        if (m >= M) m = M - 1;  // clamp loads; stores guarded
        aph[mt] = Ah + (size_t)m * 256 + quad * 8;
    }

    f32x4 acc[4][4];
#pragma unroll
    for (int i = 0; i < 4; ++i)
#pragma unroll
        for (int j = 0; j < 4; ++j) acc[i][j] = (f32x4){0.f, 0.f, 0.f, 0.f};

#pragma unroll 2
    for (int kc = 0; kc < 4; ++kc) {
        int ko = kc * 32;
        bf16x8 ahf[4];
#pragma unroll
        for (int mt = 0; mt < 4; ++mt) ahf[mt] = *(const bf16x8*)(aph[mt] + ko);
#pragma unroll
        for (int nt = 0; nt < 4; ++nt) {
            bf16x8 bh = *(const bf16x8*)&Wh[nt * 16 + l16][ko + quad * 8];
            bf16x8 bl = *(const bf16x8*)&Wl[nt * 16 + l16][ko + quad * 8];
#pragma unroll
            for (int mt = 0; mt < 4; ++mt) {
                acc[mt][nt] = __builtin_amdgcn_mfma_f32_16x16x32_bf16(ahf[mt], bh, acc[mt][nt], 0, 0, 0);
                acc[mt][nt] = __builtin_amdgcn_mfma_f32_16x16x32_bf16(ahf[mt], bl, acc[mt][nt], 0, 0, 0);
            }
        }
    }

    __syncthreads();  // all reads of Wl half 1 done
    {   // restage Wl second half (k 128..255)
        int lk0 = (t & 3) * 32;
        const unsigned short* gl = Wtl + (size_t)(c0 + sr) * 256 + 128 + lk0;
        unsigned short* ll = &Wl[sr][lk0];
#pragma unroll
        for (int i = 0; i < 4; ++i)
            *(uint4*)(ll + i * 8) = *(const uint4*)(gl + i * 8);
    }
    __syncthreads();

#pragma unroll 2
    for (int kc = 4; kc < 8; ++kc) {
        int ko = kc * 32;
        int kol = ko - 128;
        bf16x8 ahf[4];
#pragma unroll
        for (int mt = 0; mt < 4; ++mt) ahf[mt] = *(const bf16x8*)(aph[mt] + ko);
#pragma unroll
        for (int nt = 0; nt < 4; ++nt) {
            bf16x8 bh = *(const bf16x8*)&Wh[nt * 16 + l16][ko + quad * 8];
            bf16x8 bl = *(const bf16x8*)&Wl[nt * 16 + l16][kol + quad * 8];
#pragma unroll
            for (int mt = 0; mt < 4; ++mt) {
                acc[mt][nt] = __builtin_amdgcn_mfma_f32_16x16x32_bf16(ahf[mt], bh, acc[mt][nt], 0, 0, 0);
                acc[mt][nt] = __builtin_amdgcn_mfma_f32_16x16x32_bf16(ahf[mt], bl, acc[mt][nt], 0, 0, 0);
            }
        }
    }

    // permuted store: per (mt,r) one ushort4 at phys cols c0 + l16*4 + {0..3}
#pragma unroll
    for (int mt = 0; mt < 4; ++mt) {
#pragma unroll
        for (int r = 0; r < 4; ++r) {
            int row = m0 + wave * 64 + mt * 16 + quad * 4 + r;
            if (row < M) {
                ushort4 sv;
                sv.x = f2bf(acc[mt][0][r]);
                sv.y = f2bf(acc[mt][1][r]);
                sv.z = f2bf(acc[mt][2][r]);
                sv.w = f2bf(acc[mt][3][r]);
                *(ushort4*)(C + (size_t)row * 256 + c0 + l16 * 4) = sv;
            }
        }
    }
}

// ---------------- aggregation dim=256 over (permuted) bf16 messages ----------------
// wave per node, half-wave per edge, 4 edges in flight per half-wave.

__global__ __launch_bounds__(256) void k_agg256(const unsigned short* __restrict__ t,
                                                const int* __restrict__ row_ptr,
                                                const int2* __restrict__ eg,
                                                const float* __restrict__ bias,
                                                unsigned short* __restrict__ outh, int n) {
    int lane = threadIdx.x & 63;
    int wave = threadIdx.x >> 6;
    int node = blockIdx.x * 4 + wave;
    if (node >= n) return;
    int half = lane >> 5;
    int fl = lane & 31;
    int beg = row_ptr[node], end = row_ptr[node + 1];
    float acc[8] = {};
    const unsigned short* tp = t + fl * 8;

    int e = beg + half;
    for (; e + 6 < end; e += 8) {
        int2 a = eg[e], b = eg[e + 2], c = eg[e + 4], d = eg[e + 6];
        uint4 v0 = *(const uint4*)(tp + (size_t)a.x * 256);
        uint4 v1 = *(const uint4*)(tp + (size_t)b.x * 256);
        uint4 v2 = *(const uint4*)(tp + (size_t)c.x * 256);
        uint4 v3 = *(const uint4*)(tp + (size_t)d.x * 256);
        acc8(acc, v0, __int_as_float(a.y));
        acc8(acc, v1, __int_as_float(b.y));
        acc8(acc, v2, __int_as_float(c.y));
        acc8(acc, v3, __int_as_float(d.y));
    }
    for (; e + 2 < end; e += 4) {
        int2 a = eg[e], b = eg[e + 2];
        uint4 v0 = *(const uint4*)(tp + (size_t)a.x * 256);
        uint4 v1 = *(const uint4*)(tp + (size_t)b.x * 256);
        acc8(acc, v0, __int_as_float(a.y));
        acc8(acc, v1, __int_as_float(b.y));
    }
    if (e < end) {
        int2 a = eg[e];
        uint4 v0 = *(const uint4*)(tp + (size_t)a.x * 256);
        acc8(acc, v0, __int_as_float(a.y));
    }

#pragma unroll
    for (int i = 0; i < 8; ++i) acc[i] += __shfl_xor(acc[i], 32);

    if (half == 0) {
        ushort4 h0, h1;
#pragma unroll
        for (int j = 0; j < 8; ++j) {
            int cb = logc(fl * 8 + j);
            float v = acc[j] + bias[cb];
            v = v > 0.f ? v : 0.f;
            unsigned short h = f2bf(v);
            if (j == 0) h0.x = h;
            else if (j == 1) h0.y = h;
            else if (j == 2) h0.z = h;
            else if (j == 3) h0.w = h;
            else if (j == 4) h1.x = h;
            else if (j == 5) h1.y = h;
            else if (j == 6) h1.z = h;
            else h1.w = h;
        }
        unsigned short* oh = outh + (size_t)node * 256 + fl * 8;
        *(ushort4*)(oh + 0) = h0;
        *(ushort4*)(oh + 4) = h1;
    }
}

// ---------------- final projection [N,256]@[256,2] from (permuted) bf16 h ----------------

__global__ __launch_bounds__(256) void k_gemm_out2(const unsigned short* __restrict__ Hh,
                                                   const float* __restrict__ W3,
                                                   float* __restrict__ t2, int n) {
    int lane = threadIdx.x & 63;
    int wave = threadIdx.x >> 6;
    int row = blockIdx.x * 4 + wave;
    if (row >= n) return;
    ushort4 ah = *(const ushort4*)(Hh + (size_t)row * 256 + lane * 4);
    float v[4];
    v[0] = bf2f(ah.x);
    v[1] = bf2f(ah.y);
    v[2] = bf2f(ah.z);
    v[3] = bf2f(ah.w);
    float s0 = 0.f, s1 = 0.f;
#pragma unroll
    for (int i = 0; i < 4; ++i) {
        int c = logc(lane * 4 + i);
        float2 w = *(const float2*)(W3 + (size_t)c * 2);
        s0 += v[i] * w.x;
        s1 += v[i] * w.y;
    }
#pragma unroll
    for (int off = 32; off > 0; off >>= 1) {
        s0 += __shfl_down(s0, off);
        s1 += __shfl_down(s1, off);
    }
    if (lane == 0) {
        t2[(size_t)row * 2 + 0] = s0;
        t2[(size_t)row * 2 + 1] = s1;
    }
}

__global__ void k_agg2(const float* __restrict__ t2,
                       const int* __restrict__ row_ptr,
                       const int2* __restrict__ eg,
                       const float* __restrict__ b3,
                       float* __restrict__ out, int n) {
    int node = blockIdx.x * 256 + threadIdx.x;
    if (node >= n) return;
    int beg = row_ptr[node], end = row_ptr[node + 1];
    float a0 = 0.f, a1 = 0.f;
    for (int e = beg; e < end; ++e) {
        int2 m = eg[e];
        float w = __int_as_float(m.y);
        float2 v = *(const float2*)(t2 + (size_t)m.x * 2);
        a0 += w * v.x;
        a1 += w * v.y;
    }
    out[(size_t)node * 2 + 0] = a0 + b3[0];
    out[(size_t)node * 2 + 1] = a1 + b3[1];
}

// ---------------- launch ----------------

extern "C" void kernel_launch(void* const* d_in, const int* in_sizes, int n_in,
                              void* d_out, int out_size, void* d_ws, size_t ws_size,
                              hipStream_t stream) {
    const int N = N_NODES, E = N_EDGES;
    const float* x  = (const float*)d_in[0];
    const int* ei   = (const int*)d_in[1];
    const int* esrc = ei;
    const int* edst = ei + E;
    const float* W0 = (const float*)d_in[2];
    const float* b0 = (const float*)d_in[3];
    const float* W1 = (const float*)d_in[4];
    const float* b1 = (const float*)d_in[5];
    const float* W2 = (const float*)d_in[6];
    const float* b2 = (const float*)d_in[7];
    const float* W3 = (const float*)d_in[8];
    const float* b3 = (const float*)d_in[9];
    float* out = (float*)d_out;

    // workspace carve (8B-aligned regions first)
    unsigned short* Ahh = (unsigned short*)d_ws;            // N*256 bf16 h
    unsigned short* Tb  = Ahh + (size_t)N * 256;            // N*256 bf16 messages
    unsigned short* Wth = Tb + (size_t)N * 256;             // 3 x 256*256
    unsigned short* Wtl = Wth + 3 * 65536;                  // 3 x 256*256
    int2*  eg     = (int2*)(Wtl + 3 * 65536);               // E+N interleaved edge recs
    float* t2     = (float*)(eg + (E + N));                 // N*2
    float* dis    = t2 + (size_t)N * 2;                     // N
    int*   cnt    = (int*)(dis + N);                        // N
    int*   row_ptr= cnt + N;                                // N+1
    int*   pos    = row_ptr + (N + 1);                      // N
    int*   blk    = pos + N;                                // cdiv(N,1024)

    const int NB = cdiv(N, 1024);

    // CSR build
    hipMemsetAsync(cnt, 0, (size_t)N * sizeof(int), stream);
    k_count<<<cdiv(E, 256), 256, 0, stream>>>(edst, cnt, E);
    k_scan1<<<NB, 256, 0, stream>>>(cnt, row_ptr, dis, blk, N);
    k_scan2<<<1, 256, 0, stream>>>(blk, row_ptr + N, NB);
    k_scan3<<<NB, 256, 0, stream>>>(row_ptr, pos, blk, N);
    k_fill<<<cdiv(E + N, 256), 256, 0, stream>>>(esrc, edst, pos, dis, eg, E, N);

    const int ggrid = GEMM_RB * 4;
    const int agrid = cdiv(N, 4);
    const long total4 = (long)N * 64;
    const int CA = cdiv((int)total4, 256);

    k_prep<<<768 + CA, 256, 0, stream>>>(W0, W1, W2, Wth, Wtl, x, Ahh, total4);

    // layer 0
    k_gemm_mfma<<<ggrid, 256, 0, stream>>>(Ahh, Wth, Wtl, Tb, N);
    k_agg256<<<agrid, 256, 0, stream>>>(Tb, row_ptr, eg, b0, Ahh, N);
    // layer 1
    k_gemm_mfma<<<ggrid, 256, 0, stream>>>(Ahh, Wth + 65536, Wtl + 65536, Tb, N);
    k_agg256<<<agrid, 256, 0, stream>>>(Tb, row_ptr, eg, b1, Ahh, N);
    // layer 2
    k_gemm_mfma<<<ggrid, 256, 0, stream>>>(Ahh, Wth + 2 * 65536, Wtl + 2 * 65536, Tb, N);
    k_agg256<<<agrid, 256, 0, stream>>>(Tb, row_ptr, eg, b2, Ahh, N);
    // layer 3 (no relu)
    k_gemm_out2<<<agrid, 256, 0, stream>>>(Ahh, W3, t2, N);
    k_agg2<<<cdiv(N, 256), 256, 0, stream>>>(t2, row_ptr, eg, b3, out, N);
}